// Round 5
// baseline (379.970 us; speedup 1.0000x reference)
//
#include <hip/hip_runtime.h>
#include <stdint.h>

typedef unsigned short u16;
typedef __attribute__((ext_vector_type(8))) short bf16x8;
typedef __attribute__((ext_vector_type(8))) u16 u16x8;
typedef __attribute__((ext_vector_type(4))) float f32x4;

#define B_ 16
#define S_ 1024
#define D_ 768
#define H_ 12

__device__ __forceinline__ float bf2f(u16 u) {
  unsigned int x = ((unsigned int)u) << 16;
  float f;
  __builtin_memcpy(&f, &x, 4);
  return f;
}
__device__ __forceinline__ u16 f2bf(float f) {
  unsigned int x;
  __builtin_memcpy(&x, &f, 4);
  x += 0x7fffu + ((x >> 16) & 1u);
  return (u16)(x >> 16);
}

#define MFMA16(a, b, c) __builtin_amdgcn_mfma_f32_16x16x32_bf16((a), (b), (c), 0, 0, 0)

#define GLD16(g, l)                                              \
  __builtin_amdgcn_global_load_lds(                              \
      (const __attribute__((address_space(1))) void*)(g),        \
      (__attribute__((address_space(3))) void*)(l), 16, 0, 0)

// ---------------------------------------------------------------------------
// f32 -> bf16 elementwise convert (vectorized, 8 elems/thread)
// ---------------------------------------------------------------------------
__global__ __launch_bounds__(256) void cvt_bf16(const float* __restrict__ in,
                                                u16* __restrict__ out, int n8) {
  const int i = blockIdx.x * 256 + threadIdx.x;
  if (i >= n8) return;
  const float4 a = *(const float4*)(in + (size_t)i * 8);
  const float4 b = *(const float4*)(in + (size_t)i * 8 + 4);
  u16x8 o;
  o[0] = f2bf(a.x); o[1] = f2bf(a.y); o[2] = f2bf(a.z); o[3] = f2bf(a.w);
  o[4] = f2bf(b.x); o[5] = f2bf(b.y); o[6] = f2bf(b.z); o[7] = f2bf(b.w);
  *(u16x8*)(out + (size_t)i * 8) = o;
}

// ---------------------------------------------------------------------------
// Transpose + convert: W f32 [K,N] -> Wt bf16 [N,K], 32x32 LDS tiles
// ---------------------------------------------------------------------------
__global__ __launch_bounds__(256) void transpose_cvt(const float* __restrict__ W,
                                                     u16* __restrict__ Wt, int K, int N) {
  __shared__ u16 t[32][33];
  const int n0 = blockIdx.x * 32, k0 = blockIdx.y * 32;
  const int tx = threadIdx.x & 31, ty = threadIdx.x >> 5;
#pragma unroll
  for (int i = 0; i < 32; i += 8)
    t[ty + i][tx] = f2bf(W[(size_t)(k0 + ty + i) * N + n0 + tx]);
  __syncthreads();
#pragma unroll
  for (int i = 0; i < 32; i += 8) Wt[(size_t)(n0 + ty + i) * K + k0 + tx] = t[tx][ty + i];
}

// ---------------------------------------------------------------------------
// 128x128x32 MFMA GEMM, C = A[M,K] @ Bt[N,K]^T + bias (bias f32).
// global_load_lds staging (verified by r2==r3 agreement).
// MODE 0: QKV epilogue -> Q,K row-major bf16 + V transposed [B,H,HS,S] bf16
// MODE 1: f32 row-major C = Of[M,N]   (d_out is FLOAT32)
// ---------------------------------------------------------------------------
template <int MODE>
__global__ __launch_bounds__(256) void gemm_bt(const u16* __restrict__ A,
                                               const u16* __restrict__ Bt,
                                               const float* __restrict__ bias,
                                               u16* __restrict__ O0, u16* __restrict__ O1,
                                               u16* __restrict__ O2, float* __restrict__ Of,
                                               int M, int N, int K) {
  __shared__ u16 Al[128 * 32];
  __shared__ u16 Bl[128 * 32];
  const int tid = threadIdx.x;
  const int wid = tid >> 6, lane = tid & 63;
  const int lo = lane & 15, hi = lane >> 4;
  const int wr = wid >> 1, wc = wid & 1;
  const int m0 = blockIdx.x * 128, n0 = blockIdx.y * 128;
  const int rA = lane >> 2;        // 0..15 row within 16-row chunk
  const int kc = (lane & 3) * 8;   // k element chunk
  f32x4 acc[4][4] = {};
  const int kiters = K >> 5;
  for (int kt = 0; kt < kiters; ++kt) {
    const int k0 = kt * 32;
    __syncthreads();  // prior tile's fragment reads complete
#pragma unroll
    for (int ld = 0; ld < 2; ++ld) {
      const int row = ld * 64 + wid * 16 + rA;
      const int boff = ld * 4096 + wid * 1024;  // wave-uniform LDS byte base
      GLD16(A + (size_t)(m0 + row) * K + k0 + kc, (char*)Al + boff);
      GLD16(Bt + (size_t)(n0 + row) * K + k0 + kc, (char*)Bl + boff);
    }
    __syncthreads();  // staging complete (barrier drains vmcnt)
    bf16x8 af[4], bfr[4];
#pragma unroll
    for (int i = 0; i < 4; ++i)
      af[i] = *(const bf16x8*)&Al[(wr * 64 + i * 16 + lo) * 32 + hi * 8];
#pragma unroll
    for (int j = 0; j < 4; ++j)
      bfr[j] = *(const bf16x8*)&Bl[(wc * 64 + j * 16 + lo) * 32 + hi * 8];
#pragma unroll
    for (int i = 0; i < 4; ++i)
#pragma unroll
      for (int j = 0; j < 4; ++j) acc[i][j] = MFMA16(af[i], bfr[j], acc[i][j]);
  }
  // Epilogue. C/D layout: col = lane&15, row = (lane>>4)*4 + r  [verified m89/m91]
#pragma unroll
  for (int j = 0; j < 4; ++j) {
    const int n = n0 + wc * 64 + j * 16 + lo;
    const float bv = bias[n];
#pragma unroll
    for (int i = 0; i < 4; ++i) {
#pragma unroll
      for (int r = 0; r < 4; ++r) {
        const int m = m0 + wr * 64 + i * 16 + hi * 4 + r;
        const float fv = acc[i][j][r] + bv;
        if (MODE == 0) {
          const u16 o = f2bf(fv);
          if (n0 < D_) {
            O0[(size_t)m * D_ + n] = o;  // Q row-major
          } else if (n0 < 2 * D_) {
            O1[(size_t)m * D_ + (n - D_)] = o;  // K row-major
          } else {
            const int np = n - 2 * D_;  // V -> V^T [B,H,HS,S]
            O2[(((size_t)(m >> 10) * H_ + (np >> 6)) * 64 + (np & 63)) * S_ + (m & 1023)] = o;
          }
        } else {
          Of[(size_t)m * N + n] = fv;  // f32 output
        }
      }
    }
  }
}

// ---------------------------------------------------------------------------
// Flash attention: 1 block = (b, h, 64 q-rows), 4 waves x 16 q-rows, KV tiles of 32.
// Q pre-scaled by 1/8 (exact in bf16). Softmax wave-parallel via shfl_xor over
// the 16-lane column group. P goes through per-wave LDS to reach A-frag layout.
// (Verified by r3==r4 agreement with the scalar VALU reference implementation.)
// ---------------------------------------------------------------------------
__global__ __launch_bounds__(256) void attn_fwd(const u16* __restrict__ Qb,
                                                const u16* __restrict__ Kb,
                                                const u16* __restrict__ VTb,
                                                u16* __restrict__ att) {
  __shared__ u16 Kl[32 * 88];      // [kv=32][hs=64 pad->88] stride 176B
  __shared__ u16 Vl[64 * 56];      // [hs=64][kv=32 pad->56] stride 112B
  __shared__ u16 Pl[4][16 * 40];   // per-wave [q=16][kv=32 pad->40] stride 80B
  const int tid = threadIdx.x;
  const int wid = tid >> 6, lane = tid & 63;
  const int lo = lane & 15, hi = lane >> 4;
  const int q0 = blockIdx.x * 64, h = blockIdx.y, b = blockIdx.z;
  const int qw = q0 + wid * 16;
  const size_t rowbase = (size_t)b * S_;

  // Q fragments (registers for whole kernel), pre-scaled by 0.125 (=1/sqrt(64))
  bf16x8 qa[2];
  {
    const u16* qp = Qb + (rowbase + qw + lo) * D_ + h * 64;
#pragma unroll
    for (int c = 0; c < 2; ++c) {
      bf16x8 v = *(const bf16x8*)(qp + c * 32 + hi * 8);
#pragma unroll
      for (int j = 0; j < 8; ++j) v[j] = (short)f2bf(bf2f((u16)v[j]) * 0.125f);
      qa[c] = v;
    }
  }

  float mrun[4], lrun[4];
  f32x4 oacc[4] = {};
#pragma unroll
  for (int r = 0; r < 4; ++r) {
    mrun[r] = -3.0e38f;
    lrun[r] = 0.0f;
  }

  const int kvend = q0 + 64;  // causal: this block needs kv < q0+64
  for (int kv0 = 0; kv0 < kvend; kv0 += 32) {
    __syncthreads();  // previous tile's LDS reads done
    {
      const int kr = tid >> 3, kcc = (tid & 7) * 8;
      *(int4*)&Kl[kr * 88 + kcc] =
          *(const int4*)(Kb + (rowbase + kv0 + kr) * D_ + h * 64 + kcc);
      const int vr = tid >> 2, vcc = (tid & 3) * 8;
      *(int4*)&Vl[vr * 56 + vcc] =
          *(const int4*)(VTb + (((size_t)b * H_ + h) * 64 + vr) * S_ + kv0 + vcc);
    }
    __syncthreads();  // staging visible
    if (kv0 > qw + 15) continue;  // fully masked for this wave (wave-uniform)

    // QK^T: scores 16q x 32kv, K-dim = hs = 64 -> 2 MFMAs per 16-col tile
    f32x4 sc[2];
#pragma unroll
    for (int t = 0; t < 2; ++t) {
      f32x4 c = {};
      c = MFMA16(qa[0], *(const bf16x8*)&Kl[(t * 16 + lo) * 88 + hi * 8], c);
      c = MFMA16(qa[1], *(const bf16x8*)&Kl[(t * 16 + lo) * 88 + 32 + hi * 8], c);
      sc[t] = c;
    }
    const bool needmask = (kv0 + 31 > qw);
    float fsc[4];
#pragma unroll
    for (int r = 0; r < 4; ++r) {
      float s0 = sc[0][r], s1 = sc[1][r];
      if (needmask) {
        const int qg = qw + hi * 4 + r;
        if (kv0 + lo > qg) s0 = -1.0e6f;
        if (kv0 + 16 + lo > qg) s1 = -1.0e6f;
      }
      float rm = fmaxf(s0, s1);
      rm = fmaxf(rm, __shfl_xor(rm, 1));
      rm = fmaxf(rm, __shfl_xor(rm, 2));
      rm = fmaxf(rm, __shfl_xor(rm, 4));
      rm = fmaxf(rm, __shfl_xor(rm, 8));
      const float mn = fmaxf(mrun[r], rm);
      const float f = __expf(mrun[r] - mn);
      const float p0 = __expf(s0 - mn), p1 = __expf(s1 - mn);
      mrun[r] = mn;
      fsc[r] = f;
      float rs = p0 + p1;
      rs += __shfl_xor(rs, 1);
      rs += __shfl_xor(rs, 2);
      rs += __shfl_xor(rs, 4);
      rs += __shfl_xor(rs, 8);
      lrun[r] = lrun[r] * f + rs;
      Pl[wid][(hi * 4 + r) * 40 + lo] = f2bf(p0);
      Pl[wid][(hi * 4 + r) * 40 + 16 + lo] = f2bf(p1);
    }
    // same-wave LDS write->read ordering
    asm volatile("s_waitcnt lgkmcnt(0)" ::: "memory");
    const bf16x8 pa = *(const bf16x8*)&Pl[wid][lo * 40 + hi * 8];
#pragma unroll
    for (int f4 = 0; f4 < 4; ++f4) {
      f32x4 o = oacc[f4];
#pragma unroll
      for (int r = 0; r < 4; ++r) o[r] *= fsc[r];
      oacc[f4] = MFMA16(pa, *(const bf16x8*)&Vl[(f4 * 16 + lo) * 56 + hi * 8], o);
    }
  }
  // epilogue: O / l, bf16 store to att[B,S,D]
#pragma unroll
  for (int r = 0; r < 4; ++r) {
    const float inv = 1.0f / lrun[r];
    u16* op = att + (rowbase + qw + hi * 4 + r) * D_ + h * 64;
#pragma unroll
    for (int f4 = 0; f4 < 4; ++f4) op[f4 * 16 + lo] = f2bf(oacc[f4][r] * inv);
  }
}

// ---------------------------------------------------------------------------
extern "C" void kernel_launch(void* const* d_in, const int* in_sizes, int n_in, void* d_out,
                              int out_size, void* d_ws, size_t ws_size, hipStream_t stream) {
  // Assign inputs by unique element count (robust to input ordering).
  const float *x = nullptr, *Wqkv = nullptr, *bqkv = nullptr, *Wo = nullptr, *bo = nullptr;
  for (int i = 0; i < n_in; ++i) {
    switch (in_sizes[i]) {
      case 16384 * 768:  x = (const float*)d_in[i]; break;     // [16,1024,768]
      case 768 * 2304:   Wqkv = (const float*)d_in[i]; break;  // [768,2304]
      case 2304:         bqkv = (const float*)d_in[i]; break;  // [2304]
      case 768 * 768:    Wo = (const float*)d_in[i]; break;    // [768,768]
      case 768:          bo = (const float*)d_in[i]; break;    // [768]
    }
  }
  float* out = (float*)d_out;  // [16,1024,768] FLOAT32 (reference output dtype)

  char* ws = (char*)d_ws;
  u16* WqkvT = (u16*)(ws);              // 2304*768*2  = 3,538,944
  u16* WoT = (u16*)(ws + 3538944);      // 768*768*2   = 1,179,648
  u16* Qb = (u16*)(ws + 4718592);       // 16384*768*2 = 25,165,824
  u16* Kb = (u16*)(ws + 29884416);      // 25,165,824
  u16* VT = (u16*)(ws + 55050240);      // 25,165,824 -> ws total 80,216,064 B
  u16* xb = (u16*)d_out;  // bf16 x staged in d_out (f32 buffer, 2x the bytes);
                          // dead before the final GEMM overwrites out with f32
  u16* att = Qb;          // alias: att region written only by the block that
                          // already register-cached the same Q region

  cvt_bf16<<<(16384 * 768 / 8 + 255) / 256, 256, 0, stream>>>(x, xb, 16384 * 768 / 8);
  transpose_cvt<<<dim3(2304 / 32, 768 / 32), 256, 0, stream>>>(Wqkv, WqkvT, 768, 2304);
  transpose_cvt<<<dim3(768 / 32, 768 / 32), 256, 0, stream>>>(Wo, WoT, 768, 768);
  gemm_bt<0><<<dim3(16384 / 128, 2304 / 128), 256, 0, stream>>>(
      xb, WqkvT, bqkv, Qb, Kb, VT, nullptr, 16384, 2304, 768);
  attn_fwd<<<dim3(S_ / 64, H_, B_), 256, 0, stream>>>(Qb, Kb, VT, att);
  gemm_bt<1><<<dim3(16384 / 128, 768 / 128), 256, 0, stream>>>(
      att, WoT, bo, nullptr, nullptr, nullptr, out, 16384, 768, 768);
}

// Round 6
// 257.424 us; speedup vs baseline: 1.4760x; 1.4760x over previous
//
#include <hip/hip_runtime.h>
#include <stdint.h>

typedef unsigned short u16;
typedef __attribute__((ext_vector_type(8))) short bf16x8;
typedef __attribute__((ext_vector_type(8))) u16 u16x8;
typedef __attribute__((ext_vector_type(4))) u16 u16x4;
typedef __attribute__((ext_vector_type(4))) float f32x4;
typedef __attribute__((ext_vector_type(16))) float f32x16;

#define B_ 16
#define S_ 1024
#define D_ 768
#define H_ 12

__device__ __forceinline__ float bf2f(u16 u) {
  unsigned int x = ((unsigned int)u) << 16;
  float f;
  __builtin_memcpy(&f, &x, 4);
  return f;
}
__device__ __forceinline__ u16 f2bf(float f) {
  unsigned int x;
  __builtin_memcpy(&x, &f, 4);
  x += 0x7fffu + ((x >> 16) & 1u);
  return (u16)(x >> 16);
}

#define MFMA16(a, b, c) __builtin_amdgcn_mfma_f32_16x16x32_bf16((a), (b), (c), 0, 0, 0)
#define MFMA32(a, b, c) __builtin_amdgcn_mfma_f32_32x32x16_bf16((a), (b), (c), 0, 0, 0)

#define GLD16(g, l)                                              \
  __builtin_amdgcn_global_load_lds(                              \
      (const __attribute__((address_space(1))) void*)(g),        \
      (__attribute__((address_space(3))) void*)(l), 16, 0, 0)

// ---------------------------------------------------------------------------
// f32 -> bf16 elementwise convert (vectorized, 8 elems/thread)
// ---------------------------------------------------------------------------
__global__ __launch_bounds__(256) void cvt_bf16(const float* __restrict__ in,
                                                u16* __restrict__ out, int n8) {
  const int i = blockIdx.x * 256 + threadIdx.x;
  if (i >= n8) return;
  const float4 a = *(const float4*)(in + (size_t)i * 8);
  const float4 b = *(const float4*)(in + (size_t)i * 8 + 4);
  u16x8 o;
  o[0] = f2bf(a.x); o[1] = f2bf(a.y); o[2] = f2bf(a.z); o[3] = f2bf(a.w);
  o[4] = f2bf(b.x); o[5] = f2bf(b.y); o[6] = f2bf(b.z); o[7] = f2bf(b.w);
  *(u16x8*)(out + (size_t)i * 8) = o;
}

// ---------------------------------------------------------------------------
// Transpose + convert: W f32 [K,N] -> Wt bf16 [N,K], 32x32 LDS tiles
// ---------------------------------------------------------------------------
__global__ __launch_bounds__(256) void transpose_cvt(const float* __restrict__ W,
                                                     u16* __restrict__ Wt, int K, int N) {
  __shared__ u16 t[32][33];
  const int n0 = blockIdx.x * 32, k0 = blockIdx.y * 32;
  const int tx = threadIdx.x & 31, ty = threadIdx.x >> 5;
#pragma unroll
  for (int i = 0; i < 32; i += 8)
    t[ty + i][tx] = f2bf(W[(size_t)(k0 + ty + i) * N + n0 + tx]);
  __syncthreads();
#pragma unroll
  for (int i = 0; i < 32; i += 8) Wt[(size_t)(n0 + ty + i) * K + k0 + tx] = t[tx][ty + i];
}

// ---------------------------------------------------------------------------
// 128x128x32 MFMA GEMM, C = A[M,K] @ Bt[N,K]^T + bias (bias f32).
// MODE 0: QKV epilogue -> Q,K row-major bf16 + V transposed [B,H,HS,S] bf16
// MODE 1: f32 row-major C = Of[M,N]   (d_out is FLOAT32)
// ---------------------------------------------------------------------------
template <int MODE>
__global__ __launch_bounds__(256) void gemm_bt(const u16* __restrict__ A,
                                               const u16* __restrict__ Bt,
                                               const float* __restrict__ bias,
                                               u16* __restrict__ O0, u16* __restrict__ O1,
                                               u16* __restrict__ O2, float* __restrict__ Of,
                                               int M, int N, int K) {
  __shared__ u16 Al[128 * 32];
  __shared__ u16 Bl[128 * 32];
  const int tid = threadIdx.x;
  const int wid = tid >> 6, lane = tid & 63;
  const int lo = lane & 15, hi = lane >> 4;
  const int wr = wid >> 1, wc = wid & 1;
  const int m0 = blockIdx.x * 128, n0 = blockIdx.y * 128;
  const int rA = lane >> 2;        // 0..15 row within 16-row chunk
  const int kc = (lane & 3) * 8;   // k element chunk
  f32x4 acc[4][4] = {};
  const int kiters = K >> 5;
  for (int kt = 0; kt < kiters; ++kt) {
    const int k0 = kt * 32;
    __syncthreads();  // prior tile's fragment reads complete
#pragma unroll
    for (int ld = 0; ld < 2; ++ld) {
      const int row = ld * 64 + wid * 16 + rA;
      const int boff = ld * 4096 + wid * 1024;  // wave-uniform LDS byte base
      GLD16(A + (size_t)(m0 + row) * K + k0 + kc, (char*)Al + boff);
      GLD16(Bt + (size_t)(n0 + row) * K + k0 + kc, (char*)Bl + boff);
    }
    __syncthreads();  // staging complete (barrier drains vmcnt)
    bf16x8 af[4], bfr[4];
#pragma unroll
    for (int i = 0; i < 4; ++i)
      af[i] = *(const bf16x8*)&Al[(wr * 64 + i * 16 + lo) * 32 + hi * 8];
#pragma unroll
    for (int j = 0; j < 4; ++j)
      bfr[j] = *(const bf16x8*)&Bl[(wc * 64 + j * 16 + lo) * 32 + hi * 8];
#pragma unroll
    for (int i = 0; i < 4; ++i)
#pragma unroll
      for (int j = 0; j < 4; ++j) acc[i][j] = MFMA16(af[i], bfr[j], acc[i][j]);
  }
  // Epilogue. C/D layout: col = lane&15, row = (lane>>4)*4 + r  [verified m89/m91]
#pragma unroll
  for (int j = 0; j < 4; ++j) {
    const int n = n0 + wc * 64 + j * 16 + lo;
    const float bv = bias[n];
#pragma unroll
    for (int i = 0; i < 4; ++i) {
#pragma unroll
      for (int r = 0; r < 4; ++r) {
        const int m = m0 + wr * 64 + i * 16 + hi * 4 + r;
        const float fv = acc[i][j][r] + bv;
        if (MODE == 0) {
          const u16 o = f2bf(fv);
          if (n0 < D_) {
            O0[(size_t)m * D_ + n] = o;  // Q row-major
          } else if (n0 < 2 * D_) {
            O1[(size_t)m * D_ + (n - D_)] = o;  // K row-major
          } else {
            const int np = n - 2 * D_;  // V -> V^T [B,H,HS,S]
            O2[(((size_t)(m >> 10) * H_ + (np >> 6)) * 64 + (np & 63)) * S_ + (m & 1023)] = o;
          }
        } else {
          Of[(size_t)m * N + n] = fv;  // f32 output
        }
      }
    }
  }
}

// ---------------------------------------------------------------------------
// Flash attention v2 (swapped-operand 32x32 MFMA, in-register softmax).
// 1 block = (b, h, 128 q-rows), 4 waves x 32 q-rows. KV tiles of 32.
// QK^T: S^T = mfma32(Kfrag, Qfrag) -> lane owns q = lane&31 (C col), holds 16
//   kv values at rows (r&3)+8*(r>>2)+4*(lane>>5)  [C/D map verified m74/m101].
// Softmax: in-lane tree + 1 shfl_xor(32) for max and for sum.
// PV: O^T = mfma32(Vfrag, Pfrag) -> lane keeps owning q; P fragments built
//   in-register via 4 pre-selected shfl_xor(32) of packed bf16 pairs.
// K/V LDS: gathered fragment layout; every read/write is lane-linear 16B
//   (conflict-free) and staging is global_load_lds with wave-uniform dest.
// ---------------------------------------------------------------------------
__global__ __launch_bounds__(256) void attn_fwd2(const u16* __restrict__ Qb,
                                                 const u16* __restrict__ Kb,
                                                 const u16* __restrict__ VTb,
                                                 u16* __restrict__ att) {
  __shared__ u16 Kl[2048];  // 4 KB: chunk (c*64 + hi1*32 + kv) * 16B
  __shared__ u16 Vl[2048];  // 4 KB: chunk ((kvch*2+dblk)*64 + hi1*32 + d31) * 16B
  const int tid = threadIdx.x;
  const int lane = tid & 63, wid = tid >> 6;
  const int l31 = lane & 31, hi1 = lane >> 5;
  // XCD-aware remap: co-locate the 8 q-blocks of one (b,h) on one XCD.
  const int L = blockIdx.x + 8 * (blockIdx.y + 12 * blockIdx.z);
  const int bx = (L >> 3) & 7;
  const int P = (L & 7) + 8 * (L >> 6);
  const int h = P % 12, b = P / 12;
  const int q0 = bx * 128;
  const int qw0 = q0 + wid * 32;
  const int qg = qw0 + l31;  // this lane's q-row
  const size_t rowbase = (size_t)b * S_;

  // Q fragments (B-operand of swapped QK^T): lane holds Q[qg][c*16+hi1*8+j]/8
  bf16x8 qf[4];
  {
    const u16* qp = Qb + (rowbase + qg) * D_ + h * 64 + hi1 * 8;
#pragma unroll
    for (int c = 0; c < 4; ++c) {
      bf16x8 v = *(const bf16x8*)(qp + c * 16);
#pragma unroll
      for (int j = 0; j < 8; ++j) v[j] = (short)f2bf(bf2f((u16)v[j]) * 0.125f);
      qf[c] = v;
    }
  }
  float mrun = -3.0e38f, lrun = 0.0f;
  f32x16 o0 = {}, o1 = {};

  // Staging: thread t's data lands at LDS byte t*16 (= wave base + lane*16).
  const u16* kgp =
      Kb + (rowbase + (tid & 31)) * D_ + h * 64 + (tid >> 6) * 16 + ((tid >> 5) & 1) * 8;
  const u16* vgp = VTb +
                   (((size_t)b * H_ + h) * 64 + ((tid >> 6) & 1) * 32 + (tid & 31)) * S_ +
                   (tid >> 7) * 16 + ((tid >> 5) & 1) * 8;
  char* kdst = (char*)Kl + wid * 1024;  // wave-uniform dest
  char* vdst = (char*)Vl + wid * 1024;
  const char* kbase = (const char*)Kl + lane * 16;
  const char* vbase = (const char*)Vl + lane * 16;

  const int kvend = q0 + 128;  // causal bound for this block
  for (int kv0 = 0; kv0 < kvend; kv0 += 32) {
    __syncthreads();  // prior tile's fragment reads complete
    GLD16(kgp + (size_t)kv0 * D_, kdst);
    GLD16(vgp + kv0, vdst);
    __syncthreads();  // staging visible
    if (kv0 > qw0 + 31) continue;  // fully masked for this wave (wave-uniform)

    // QK^T: 4 MFMAs over d-chunks of 16
    f32x16 s = {};
#pragma unroll
    for (int c = 0; c < 4; ++c) s = MFMA32(*(const bf16x8*)(kbase + c * 1024), qf[c], s);

    if (kv0 + 31 > qw0) {  // diagonal tile: causal mask
#pragma unroll
      for (int r = 0; r < 16; ++r) {
        const int kvg = kv0 + (r & 3) + 8 * (r >> 2) + 4 * hi1;
        if (kvg > qg) s[r] = -1.0e30f;
      }
    }
    // online softmax: in-lane reduce + 1 shfl to the partner half-row
    float rm = s[0];
#pragma unroll
    for (int r = 1; r < 16; ++r) rm = fmaxf(rm, s[r]);
    rm = fmaxf(rm, __shfl_xor(rm, 32));
    const float mn = fmaxf(mrun, rm);
    const float fr = __expf(mrun - mn);
    mrun = mn;
    float p[16];
    float rs = 0.0f;
#pragma unroll
    for (int r = 0; r < 16; ++r) {
      p[r] = __expf(s[r] - mn);
      rs += p[r];
    }
    rs += __shfl_xor(rs, 32);
    lrun = lrun * fr + rs;
#pragma unroll
    for (int r = 0; r < 16; ++r) {
      o0[r] *= fr;
      o1[r] *= fr;
    }
    // pack P to bf16 pairs; 4 shfls build both PV B-fragments in-register
    unsigned int pa[4], pb[4];
#pragma unroll
    for (int g = 0; g < 4; ++g) {
      pa[g] = (unsigned)f2bf(p[4 * g]) | ((unsigned)f2bf(p[4 * g + 1]) << 16);
      pb[g] = (unsigned)f2bf(p[4 * g + 2]) | ((unsigned)f2bf(p[4 * g + 3]) << 16);
    }
    const unsigned sa = __shfl_xor(hi1 ? pa[0] : pa[1], 32);
    const unsigned sb = __shfl_xor(hi1 ? pb[0] : pb[1], 32);
    const unsigned sc = __shfl_xor(hi1 ? pa[2] : pa[3], 32);
    const unsigned sd = __shfl_xor(hi1 ? pb[2] : pb[3], 32);
    const uint4 w0 = hi1 ? make_uint4(sa, sb, pa[1], pb[1]) : make_uint4(pa[0], pb[0], sa, sb);
    const uint4 w1 = hi1 ? make_uint4(sc, sd, pa[3], pb[3]) : make_uint4(pa[2], pb[2], sc, sd);
    bf16x8 pf0, pf1;
    __builtin_memcpy(&pf0, &w0, 16);
    __builtin_memcpy(&pf1, &w1, 16);
    // PV: O^T += V^T_chunk . P^T  (4 MFMAs: kvchunk x dblk)
    o0 = MFMA32(*(const bf16x8*)(vbase + 0 * 1024), pf0, o0);
    o1 = MFMA32(*(const bf16x8*)(vbase + 1 * 1024), pf0, o1);
    o0 = MFMA32(*(const bf16x8*)(vbase + 2 * 1024), pf1, o0);
    o1 = MFMA32(*(const bf16x8*)(vbase + 3 * 1024), pf1, o1);
  }
  // epilogue: lane owns q; rows are d-offsets (r&3)+8*(r>>2)+4*hi1
  const float inv = 1.0f / lrun;
  u16* op = att + (rowbase + qg) * D_ + h * 64;
#pragma unroll
  for (int g = 0; g < 4; ++g) {
    u16x4 v0, v1;
#pragma unroll
    for (int j = 0; j < 4; ++j) {
      v0[j] = f2bf(o0[4 * g + j] * inv);
      v1[j] = f2bf(o1[4 * g + j] * inv);
    }
    *(u16x4*)(op + 8 * g + 4 * hi1) = v0;
    *(u16x4*)(op + 32 + 8 * g + 4 * hi1) = v1;
  }
}

// ---------------------------------------------------------------------------
extern "C" void kernel_launch(void* const* d_in, const int* in_sizes, int n_in, void* d_out,
                              int out_size, void* d_ws, size_t ws_size, hipStream_t stream) {
  // Assign inputs by unique element count (robust to input ordering).
  const float *x = nullptr, *Wqkv = nullptr, *bqkv = nullptr, *Wo = nullptr, *bo = nullptr;
  for (int i = 0; i < n_in; ++i) {
    switch (in_sizes[i]) {
      case 16384 * 768:  x = (const float*)d_in[i]; break;     // [16,1024,768]
      case 768 * 2304:   Wqkv = (const float*)d_in[i]; break;  // [768,2304]
      case 2304:         bqkv = (const float*)d_in[i]; break;  // [2304]
      case 768 * 768:    Wo = (const float*)d_in[i]; break;    // [768,768]
      case 768:          bo = (const float*)d_in[i]; break;    // [768]
    }
  }
  float* out = (float*)d_out;  // [16,1024,768] FLOAT32

  char* ws = (char*)d_ws;
  u16* WqkvT = (u16*)(ws);              // 2304*768*2  = 3,538,944
  u16* WoT = (u16*)(ws + 3538944);      // 768*768*2   = 1,179,648
  u16* Qb = (u16*)(ws + 4718592);       // 16384*768*2 = 25,165,824
  u16* Kb = (u16*)(ws + 29884416);      // 25,165,824
  u16* VT = (u16*)(ws + 55050240);      // 25,165,824 -> ws total 80,216,064 B
  u16* xb = (u16*)d_out;  // bf16 x staged in d_out; dead before final GEMM
  u16* att = Qb;          // alias: block reads its own Q region before writing

  cvt_bf16<<<(16384 * 768 / 8 + 255) / 256, 256, 0, stream>>>(x, xb, 16384 * 768 / 8);
  transpose_cvt<<<dim3(2304 / 32, 768 / 32), 256, 0, stream>>>(Wqkv, WqkvT, 768, 2304);
  transpose_cvt<<<dim3(768 / 32, 768 / 32), 256, 0, stream>>>(Wo, WoT, 768, 768);
  gemm_bt<0><<<dim3(16384 / 128, 2304 / 128), 256, 0, stream>>>(
      xb, WqkvT, bqkv, Qb, Kb, VT, nullptr, 16384, 2304, 768);
  attn_fwd2<<<dim3(8, H_, B_), 256, 0, stream>>>(Qb, Kb, VT, att);
  gemm_bt<1><<<dim3(16384 / 128, 768 / 128), 256, 0, stream>>>(
      att, WoT, bo, nullptr, nullptr, nullptr, out, 16384, 768, 768);
}

// Round 7
// 251.875 us; speedup vs baseline: 1.5086x; 1.0220x over previous
//
#include <hip/hip_runtime.h>
#include <stdint.h>

typedef unsigned short u16;
typedef __attribute__((ext_vector_type(8))) short bf16x8;
typedef __attribute__((ext_vector_type(8))) u16 u16x8;
typedef __attribute__((ext_vector_type(4))) u16 u16x4;
typedef __attribute__((ext_vector_type(4))) float f32x4;
typedef __attribute__((ext_vector_type(16))) float f32x16;

#define B_ 16
#define S_ 1024
#define D_ 768
#define H_ 12

__device__ __forceinline__ float bf2f(u16 u) {
  unsigned int x = ((unsigned int)u) << 16;
  float f;
  __builtin_memcpy(&f, &x, 4);
  return f;
}
__device__ __forceinline__ u16 f2bf(float f) {
  unsigned int x;
  __builtin_memcpy(&x, &f, 4);
  x += 0x7fffu + ((x >> 16) & 1u);
  return (u16)(x >> 16);
}

#define MFMA16(a, b, c) __builtin_amdgcn_mfma_f32_16x16x32_bf16((a), (b), (c), 0, 0, 0)
#define MFMA32(a, b, c) __builtin_amdgcn_mfma_f32_32x32x16_bf16((a), (b), (c), 0, 0, 0)

#define GLD16(g, l)                                              \
  __builtin_amdgcn_global_load_lds(                              \
      (const __attribute__((address_space(1))) void*)(g),        \
      (__attribute__((address_space(3))) void*)(l), 16, 0, 0)

// ---------------------------------------------------------------------------
// f32 -> bf16 elementwise convert (vectorized, 8 elems/thread)
// ---------------------------------------------------------------------------
__global__ __launch_bounds__(256) void cvt_bf16(const float* __restrict__ in,
                                                u16* __restrict__ out, int n8) {
  const int i = blockIdx.x * 256 + threadIdx.x;
  if (i >= n8) return;
  const float4 a = *(const float4*)(in + (size_t)i * 8);
  const float4 b = *(const float4*)(in + (size_t)i * 8 + 4);
  u16x8 o;
  o[0] = f2bf(a.x); o[1] = f2bf(a.y); o[2] = f2bf(a.z); o[3] = f2bf(a.w);
  o[4] = f2bf(b.x); o[5] = f2bf(b.y); o[6] = f2bf(b.z); o[7] = f2bf(b.w);
  *(u16x8*)(out + (size_t)i * 8) = o;
}

// ---------------------------------------------------------------------------
// Transpose + convert: W f32 [K,N] -> Wt bf16 [N,K], 32x32 LDS tiles
// ---------------------------------------------------------------------------
__global__ __launch_bounds__(256) void transpose_cvt(const float* __restrict__ W,
                                                     u16* __restrict__ Wt, int K, int N) {
  __shared__ u16 t[32][33];
  const int n0 = blockIdx.x * 32, k0 = blockIdx.y * 32;
  const int tx = threadIdx.x & 31, ty = threadIdx.x >> 5;
#pragma unroll
  for (int i = 0; i < 32; i += 8)
    t[ty + i][tx] = f2bf(W[(size_t)(k0 + ty + i) * N + n0 + tx]);
  __syncthreads();
#pragma unroll
  for (int i = 0; i < 32; i += 8) Wt[(size_t)(n0 + ty + i) * K + k0 + tx] = t[tx][ty + i];
}

// ---------------------------------------------------------------------------
// 128x128x32 MFMA GEMM, C = A[M,K] @ Bt[N,K]^T + bias (bias f32).
// 2-phase double-buffered LDS (T3-minimum recipe): STAGE(next) -> ds_read+MFMA
// (cur) -> vmcnt(0) -> raw s_barrier. One barrier per K-step; next-tile loads
// fly under the compute phase (no __syncthreads vmcnt(0)-drain before compute).
// MODE 0: QKV epilogue -> Q,K row-major bf16 + V transposed [B,H,HS,S] bf16
// MODE 1: f32 row-major C = Of[M,N]   (d_out is FLOAT32)
// ---------------------------------------------------------------------------
template <int MODE>
__global__ __launch_bounds__(256) void gemm_bt(const u16* __restrict__ A,
                                               const u16* __restrict__ Bt,
                                               const float* __restrict__ bias,
                                               u16* __restrict__ O0, u16* __restrict__ O1,
                                               u16* __restrict__ O2, float* __restrict__ Of,
                                               int M, int N, int K) {
  __shared__ u16 Al[2 * 128 * 32];  // 2 x 8 KB
  __shared__ u16 Bl[2 * 128 * 32];
  const int tid = threadIdx.x;
  const int wid = tid >> 6, lane = tid & 63;
  const int lo = lane & 15, hi = lane >> 4;
  const int wr = wid >> 1, wc = wid & 1;
  const int m0 = blockIdx.x * 128, n0 = blockIdx.y * 128;
  const int rA = lane >> 2;        // 0..15 row within 16-row chunk
  const int kc = (lane & 3) * 8;   // k element chunk
  const int srow = wid * 16 + rA;  // staging row (0..63)
  f32x4 acc[4][4] = {};
  const int kiters = K >> 5;

  // prologue: stage tile 0 into buf 0, drain, barrier
  GLD16(A + (size_t)(m0 + srow) * K + kc, (char*)Al + wid * 1024);
  GLD16(A + (size_t)(m0 + srow + 64) * K + kc, (char*)Al + 4096 + wid * 1024);
  GLD16(Bt + (size_t)(n0 + srow) * K + kc, (char*)Bl + wid * 1024);
  GLD16(Bt + (size_t)(n0 + srow + 64) * K + kc, (char*)Bl + 4096 + wid * 1024);
  asm volatile("s_waitcnt vmcnt(0)" ::: "memory");
  __builtin_amdgcn_s_barrier();

  int cur = 0;
  for (int kt = 0; kt < kiters; ++kt) {
    // stage next K-tile into the other buffer (loads overlap compute below)
    if (kt + 1 < kiters) {
      const int k0 = (kt + 1) * 32;
      const int nb = (cur ^ 1) * 8192;
      GLD16(A + (size_t)(m0 + srow) * K + k0 + kc, (char*)Al + nb + wid * 1024);
      GLD16(A + (size_t)(m0 + srow + 64) * K + k0 + kc, (char*)Al + nb + 4096 + wid * 1024);
      GLD16(Bt + (size_t)(n0 + srow) * K + k0 + kc, (char*)Bl + nb + wid * 1024);
      GLD16(Bt + (size_t)(n0 + srow + 64) * K + k0 + kc, (char*)Bl + nb + 4096 + wid * 1024);
    }
    const int cb = cur * 4096;  // element offset of current buffer
    bf16x8 af[4], bfr[4];
#pragma unroll
    for (int i = 0; i < 4; ++i)
      af[i] = *(const bf16x8*)&Al[cb + (wr * 64 + i * 16 + lo) * 32 + hi * 8];
#pragma unroll
    for (int j = 0; j < 4; ++j)
      bfr[j] = *(const bf16x8*)&Bl[cb + (wc * 64 + j * 16 + lo) * 32 + hi * 8];
    __builtin_amdgcn_s_setprio(1);
#pragma unroll
    for (int i = 0; i < 4; ++i)
#pragma unroll
      for (int j = 0; j < 4; ++j) acc[i][j] = MFMA16(af[i], bfr[j], acc[i][j]);
    __builtin_amdgcn_s_setprio(0);
    // next-tile loads done + all waves done reading cur -> safe to swap
    asm volatile("s_waitcnt vmcnt(0)" ::: "memory");
    __builtin_amdgcn_s_barrier();
    cur ^= 1;
  }
  // Epilogue. C/D layout: col = lane&15, row = (lane>>4)*4 + r  [verified m89/m91]
#pragma unroll
  for (int j = 0; j < 4; ++j) {
    const int n = n0 + wc * 64 + j * 16 + lo;
    const float bv = bias[n];
#pragma unroll
    for (int i = 0; i < 4; ++i) {
#pragma unroll
      for (int r = 0; r < 4; ++r) {
        const int m = m0 + wr * 64 + i * 16 + hi * 4 + r;
        const float fv = acc[i][j][r] + bv;
        if (MODE == 0) {
          const u16 o = f2bf(fv);
          if (n0 < D_) {
            O0[(size_t)m * D_ + n] = o;  // Q row-major
          } else if (n0 < 2 * D_) {
            O1[(size_t)m * D_ + (n - D_)] = o;  // K row-major
          } else {
            const int np = n - 2 * D_;  // V -> V^T [B,H,HS,S]
            O2[(((size_t)(m >> 10) * H_ + (np >> 6)) * 64 + (np & 63)) * S_ + (m & 1023)] = o;
          }
        } else {
          Of[(size_t)m * N + n] = fv;  // f32 output
        }
      }
    }
  }
}

// ---------------------------------------------------------------------------
// Flash attention v2 (swapped-operand 32x32 MFMA, in-register softmax).
// 1 block = (b, h, 128 q-rows), 4 waves x 32 q-rows. KV tiles of 32.
// ---------------------------------------------------------------------------
__global__ __launch_bounds__(256) void attn_fwd2(const u16* __restrict__ Qb,
                                                 const u16* __restrict__ Kb,
                                                 const u16* __restrict__ VTb,
                                                 u16* __restrict__ att) {
  __shared__ u16 Kl[2048];  // 4 KB: chunk (c*64 + hi1*32 + kv) * 16B
  __shared__ u16 Vl[2048];  // 4 KB: chunk ((kvch*2+dblk)*64 + hi1*32 + d31) * 16B
  const int tid = threadIdx.x;
  const int lane = tid & 63, wid = tid >> 6;
  const int l31 = lane & 31, hi1 = lane >> 5;
  // XCD-aware remap: co-locate the 8 q-blocks of one (b,h) on one XCD.
  const int L = blockIdx.x + 8 * (blockIdx.y + 12 * blockIdx.z);
  const int bx = (L >> 3) & 7;
  const int P = (L & 7) + 8 * (L >> 6);
  const int h = P % 12, b = P / 12;
  const int q0 = bx * 128;
  const int qw0 = q0 + wid * 32;
  const int qg = qw0 + l31;  // this lane's q-row
  const size_t rowbase = (size_t)b * S_;

  // Q fragments (B-operand of swapped QK^T): lane holds Q[qg][c*16+hi1*8+j]/8
  bf16x8 qf[4];
  {
    const u16* qp = Qb + (rowbase + qg) * D_ + h * 64 + hi1 * 8;
#pragma unroll
    for (int c = 0; c < 4; ++c) {
      bf16x8 v = *(const bf16x8*)(qp + c * 16);
#pragma unroll
      for (int j = 0; j < 8; ++j) v[j] = (short)f2bf(bf2f((u16)v[j]) * 0.125f);
      qf[c] = v;
    }
  }
  float mrun = -3.0e38f, lrun = 0.0f;
  f32x16 o0 = {}, o1 = {};

  // Staging: thread t's data lands at LDS byte t*16 (= wave base + lane*16).
  const u16* kgp =
      Kb + (rowbase + (tid & 31)) * D_ + h * 64 + (tid >> 6) * 16 + ((tid >> 5) & 1) * 8;
  const u16* vgp = VTb +
                   (((size_t)b * H_ + h) * 64 + ((tid >> 6) & 1) * 32 + (tid & 31)) * S_ +
                   (tid >> 7) * 16 + ((tid >> 5) & 1) * 8;
  char* kdst = (char*)Kl + wid * 1024;  // wave-uniform dest
  char* vdst = (char*)Vl + wid * 1024;
  const char* kbase = (const char*)Kl + lane * 16;
  const char* vbase = (const char*)Vl + lane * 16;

  const int kvend = q0 + 128;  // causal bound for this block
  for (int kv0 = 0; kv0 < kvend; kv0 += 32) {
    __syncthreads();  // prior tile's fragment reads complete
    GLD16(kgp + (size_t)kv0 * D_, kdst);
    GLD16(vgp + kv0, vdst);
    __syncthreads();  // staging visible
    if (kv0 > qw0 + 31) continue;  // fully masked for this wave (wave-uniform)

    // QK^T: 4 MFMAs over d-chunks of 16
    f32x16 s = {};
#pragma unroll
    for (int c = 0; c < 4; ++c) s = MFMA32(*(const bf16x8*)(kbase + c * 1024), qf[c], s);

    if (kv0 + 31 > qw0) {  // diagonal tile: causal mask
#pragma unroll
      for (int r = 0; r < 16; ++r) {
        const int kvg = kv0 + (r & 3) + 8 * (r >> 2) + 4 * hi1;
        if (kvg > qg) s[r] = -1.0e30f;
      }
    }
    // online softmax: in-lane reduce + 1 shfl to the partner half-row
    float rm = s[0];
#pragma unroll
    for (int r = 1; r < 16; ++r) rm = fmaxf(rm, s[r]);
    rm = fmaxf(rm, __shfl_xor(rm, 32));
    const float mn = fmaxf(mrun, rm);
    const float fr = __expf(mrun - mn);
    mrun = mn;
    float p[16];
    float rs = 0.0f;
#pragma unroll
    for (int r = 0; r < 16; ++r) {
      p[r] = __expf(s[r] - mn);
      rs += p[r];
    }
    rs += __shfl_xor(rs, 32);
    lrun = lrun * fr + rs;
#pragma unroll
    for (int r = 0; r < 16; ++r) {
      o0[r] *= fr;
      o1[r] *= fr;
    }
    // pack P to bf16 pairs; 4 shfls build both PV B-fragments in-register
    unsigned int pa[4], pb[4];
#pragma unroll
    for (int g = 0; g < 4; ++g) {
      pa[g] = (unsigned)f2bf(p[4 * g]) | ((unsigned)f2bf(p[4 * g + 1]) << 16);
      pb[g] = (unsigned)f2bf(p[4 * g + 2]) | ((unsigned)f2bf(p[4 * g + 3]) << 16);
    }
    const unsigned sa = __shfl_xor(hi1 ? pa[0] : pa[1], 32);
    const unsigned sb = __shfl_xor(hi1 ? pb[0] : pb[1], 32);
    const unsigned sc = __shfl_xor(hi1 ? pa[2] : pa[3], 32);
    const unsigned sd = __shfl_xor(hi1 ? pb[2] : pb[3], 32);
    const uint4 w0 = hi1 ? make_uint4(sa, sb, pa[1], pb[1]) : make_uint4(pa[0], pb[0], sa, sb);
    const uint4 w1 = hi1 ? make_uint4(sc, sd, pa[3], pb[3]) : make_uint4(pa[2], pb[2], sc, sd);
    bf16x8 pf0, pf1;
    __builtin_memcpy(&pf0, &w0, 16);
    __builtin_memcpy(&pf1, &w1, 16);
    // PV: O^T += V^T_chunk . P^T  (4 MFMAs: kvchunk x dblk)
    o0 = MFMA32(*(const bf16x8*)(vbase + 0 * 1024), pf0, o0);
    o1 = MFMA32(*(const bf16x8*)(vbase + 1 * 1024), pf0, o1);
    o0 = MFMA32(*(const bf16x8*)(vbase + 2 * 1024), pf1, o0);
    o1 = MFMA32(*(const bf16x8*)(vbase + 3 * 1024), pf1, o1);
  }
  // epilogue: lane owns q; rows are d-offsets (r&3)+8*(r>>2)+4*hi1
  const float inv = 1.0f / lrun;
  u16* op = att + (rowbase + qg) * D_ + h * 64;
#pragma unroll
  for (int g = 0; g < 4; ++g) {
    u16x4 v0, v1;
#pragma unroll
    for (int j = 0; j < 4; ++j) {
      v0[j] = f2bf(o0[4 * g + j] * inv);
      v1[j] = f2bf(o1[4 * g + j] * inv);
    }
    *(u16x4*)(op + 8 * g + 4 * hi1) = v0;
    *(u16x4*)(op + 32 + 8 * g + 4 * hi1) = v1;
  }
}

// ---------------------------------------------------------------------------
extern "C" void kernel_launch(void* const* d_in, const int* in_sizes, int n_in, void* d_out,
                              int out_size, void* d_ws, size_t ws_size, hipStream_t stream) {
  // Assign inputs by unique element count (robust to input ordering).
  const float *x = nullptr, *Wqkv = nullptr, *bqkv = nullptr, *Wo = nullptr, *bo = nullptr;
  for (int i = 0; i < n_in; ++i) {
    switch (in_sizes[i]) {
      case 16384 * 768:  x = (const float*)d_in[i]; break;     // [16,1024,768]
      case 768 * 2304:   Wqkv = (const float*)d_in[i]; break;  // [768,2304]
      case 2304:         bqkv = (const float*)d_in[i]; break;  // [2304]
      case 768 * 768:    Wo = (const float*)d_in[i]; break;    // [768,768]
      case 768:          bo = (const float*)d_in[i]; break;    // [768]
    }
  }
  float* out = (float*)d_out;  // [16,1024,768] FLOAT32

  char* ws = (char*)d_ws;
  u16* WqkvT = (u16*)(ws);              // 2304*768*2  = 3,538,944
  u16* WoT = (u16*)(ws + 3538944);      // 768*768*2   = 1,179,648
  u16* Qb = (u16*)(ws + 4718592);       // 16384*768*2 = 25,165,824
  u16* Kb = (u16*)(ws + 29884416);      // 25,165,824
  u16* VT = (u16*)(ws + 55050240);      // 25,165,824 -> ws total 80,216,064 B
  u16* xb = (u16*)d_out;  // bf16 x staged in d_out; dead before final GEMM
  u16* att = Qb;          // alias: block reads its own Q region before writing

  cvt_bf16<<<(16384 * 768 / 8 + 255) / 256, 256, 0, stream>>>(x, xb, 16384 * 768 / 8);
  transpose_cvt<<<dim3(2304 / 32, 768 / 32), 256, 0, stream>>>(Wqkv, WqkvT, 768, 2304);
  transpose_cvt<<<dim3(768 / 32, 768 / 32), 256, 0, stream>>>(Wo, WoT, 768, 768);
  gemm_bt<0><<<dim3(16384 / 128, 2304 / 128), 256, 0, stream>>>(
      xb, WqkvT, bqkv, Qb, Kb, VT, nullptr, 16384, 2304, 768);
  attn_fwd2<<<dim3(8, H_, B_), 256, 0, stream>>>(Qb, Kb, VT, att);
  gemm_bt<1><<<dim3(16384 / 128, 768 / 128), 256, 0, stream>>>(
      att, WoT, bo, nullptr, nullptr, nullptr, out, 16384, 768, 768);
}